// Round 6
// baseline (192.591 us; speedup 1.0000x reference)
//
#include <hip/hip_runtime.h>
#include <math.h>

#define HW (512*512)
#define TSX 64     // block tile cols
#define TSY 128    // block tile rows (16 bands x 8 rows)

// ---------------- Kernel 1: per-plane partial sums (global avg pool) ----------------
__global__ __launch_bounds__(256) void k_reduce(const float* __restrict__ x,
                                                float* __restrict__ ws) {
    int bid = blockIdx.x;            // 1024 blocks = 128 planes * 8 chunks
    int plane = bid >> 3, j = bid & 7;
    const float4* xv = (const float4*)x + (size_t)plane * 65536 + (size_t)j * 8192;
    int tid = threadIdx.x;
    float s = 0.f;
    #pragma unroll
    for (int k = 0; k < 32; ++k) {
        float4 v = xv[(size_t)k * 256 + tid];
        s += (v.x + v.y) + (v.z + v.w);
    }
    #pragma unroll
    for (int off = 32; off > 0; off >>= 1) s += __shfl_down(s, off, 64);
    __shared__ float red[4];
    if ((tid & 63) == 0) red[tid >> 6] = s;
    __syncthreads();
    if (tid == 0) ws[bid] = (red[0] + red[1]) + (red[2] + red[3]);
}

// ---------------- Kernel 2: finish pool + channel-attention MLP ----------------
__global__ __launch_bounds__(128) void k_mlp(const float* __restrict__ part,
                                             const float* __restrict__ w1,
                                             const float* __restrict__ b1,
                                             const float* __restrict__ w2,
                                             const float* __restrict__ b2,
                                             float* __restrict__ att_out) {
    __shared__ float pool[128];   // [b][c], b=32, c=4
    __shared__ float hbuf[64];    // [b][r], r=2
    int tid = threadIdx.x;
    float s = 0.f;
    #pragma unroll
    for (int j = 0; j < 8; ++j) s += part[tid * 8 + j];
    pool[tid] = s * (1.f / 262144.f);
    __syncthreads();
    if (tid < 64) {
        int b = tid >> 1, r = tid & 1;
        float h = b1[r];
        #pragma unroll
        for (int c = 0; c < 4; ++c) h += w1[r * 4 + c] * pool[b * 4 + c];
        hbuf[tid] = fmaxf(h, 0.f);          // hbuf[b*2+r]
    }
    __syncthreads();
    {
        int b = tid >> 2, c = tid & 3;
        float z = b2[c];
        #pragma unroll
        for (int r = 0; r < 2; ++r) z += w2[c * 2 + r] * hbuf[b * 2 + r];
        att_out[tid] = 1.f / (1.f + __expf(-z));   // att[b*4+c]
    }
}

// ---------------- Kernel 3: fused, NO LDS — register-resident conv ----------------
// Thread owns 4 cols x 8 rows. Streams 14 input rows; per row loads the 12-dword
// x window (4ch x 3 aligned float4), recomputes the gated 1x1 (p[3][12]) in regs,
// accumulates 7x7 taps into acc[8][4]. Centers recomputed in epilogue (L1-hot).
// All array indices compile-time constant (rule #20). Zero LDS, zero barriers.
__global__ __launch_bounds__(256, 4) void k_fused(const float* __restrict__ x,
                                                  const float* __restrict__ conv_w,
                                                  const float* __restrict__ conv_b,
                                                  const float* __restrict__ sa_w,
                                                  const float* __restrict__ sa_b,
                                                  const float* __restrict__ att,
                                                  float* __restrict__ out) {
    int tid = threadIdx.x;
    int b = blockIdx.z;
    int tx0 = blockIdx.x * TSX, ty0 = blockIdx.y * TSY;
    int txl = tid & 15, tyl = tid >> 4;
    int c0 = tx0 + txl * 4;      // first output col of this thread
    int r0 = ty0 + tyl * 8;      // first output row of this thread

    // uniform params (scalar loads)
    float kw[12], kb[3];
    #pragma unroll
    for (int t = 0; t < 12; ++t) kw[t] = conv_w[t] * att[b * 4 + (t & 3)];
    #pragma unroll
    for (int o = 0; o < 3; ++o) kb[o] = conv_b[o];
    float sbias = sa_b[0];
    const float* xb = x + (size_t)b * 4 * HW;

    float acc[8][4];
    #pragma unroll
    for (int i = 0; i < 8; ++i) {
        #pragma unroll
        for (int j = 0; j < 4; ++j) acc[i][j] = 0.f;
    }

    for (int k = 0; k < 14; ++k) {      // input row gy = r0 - 3 + k
        int gy = r0 - 3 + k;
        bool rv = ((unsigned)gy < 512u);
        float p[3][12];                  // gated 1x1 window, cols c0-4 .. c0+7
        #pragma unroll
        for (int j = 0; j < 3; ++j) {
            int gx0 = c0 - 4 + j * 4;    // aligned quad; fully in or out of image
            bool inb = rv && ((unsigned)gx0 < 512u);
            float4 X0 = make_float4(0.f, 0.f, 0.f, 0.f), X1 = X0, X2 = X0, X3 = X0;
            if (inb) {
                size_t off = (size_t)gy * 512 + gx0;
                X0 = *(const float4*)(xb + off);
                X1 = *(const float4*)(xb + HW + off);
                X2 = *(const float4*)(xb + 2 * HW + off);
                X3 = *(const float4*)(xb + 3 * HW + off);
            }
            #pragma unroll
            for (int oc = 0; oc < 3; ++oc) {
                float kbm = inb ? kb[oc] : 0.f;   // zero-pad outside image
                p[oc][j*4+0] = kbm + kw[oc*4+0]*X0.x + kw[oc*4+1]*X1.x + kw[oc*4+2]*X2.x + kw[oc*4+3]*X3.x;
                p[oc][j*4+1] = kbm + kw[oc*4+0]*X0.y + kw[oc*4+1]*X1.y + kw[oc*4+2]*X2.y + kw[oc*4+3]*X3.y;
                p[oc][j*4+2] = kbm + kw[oc*4+0]*X0.z + kw[oc*4+1]*X1.z + kw[oc*4+2]*X2.z + kw[oc*4+3]*X3.z;
                p[oc][j*4+3] = kbm + kw[oc*4+0]*X0.w + kw[oc*4+1]*X1.w + kw[oc*4+2]*X2.w + kw[oc*4+3]*X3.w;
            }
        }
        // accumulate 7x7 taps: out row i uses this input row with dy = k - i
        #pragma unroll
        for (int i = 0; i < 8; ++i) {
            int dy = k - i;
            if (dy >= 0 && dy < 7) {     // wave-uniform branch (k uniform, i static)
                #pragma unroll
                for (int oc = 0; oc < 3; ++oc) {
                    const float* wrow = sa_w + oc * 49 + dy * 7;
                    #pragma unroll
                    for (int dx = 0; dx < 7; ++dx) {
                        float wv = wrow[dx];         // uniform -> s_load
                        #pragma unroll
                        for (int j = 0; j < 4; ++j)
                            acc[i][j] += wv * p[oc][1 + j + dx];
                    }
                }
            }
        }
    }

    // ---- Epilogue: recompute center p (L1-hot), sigmoid gate, b128 stores ----
    float* ob = out + (size_t)b * 3 * HW;
    #pragma unroll
    for (int i = 0; i < 8; ++i) {
        size_t off = (size_t)(r0 + i) * 512 + c0;
        float4 X0 = *(const float4*)(xb + off);
        float4 X1 = *(const float4*)(xb + HW + off);
        float4 X2 = *(const float4*)(xb + 2 * HW + off);
        float4 X3 = *(const float4*)(xb + 3 * HW + off);
        float g0 = 1.f / (1.f + __expf(-(acc[i][0] + sbias)));
        float g1 = 1.f / (1.f + __expf(-(acc[i][1] + sbias)));
        float g2 = 1.f / (1.f + __expf(-(acc[i][2] + sbias)));
        float g3 = 1.f / (1.f + __expf(-(acc[i][3] + sbias)));
        #pragma unroll
        for (int oc = 0; oc < 3; ++oc) {
            float4 c;
            c.x = (kb[oc] + kw[oc*4+0]*X0.x + kw[oc*4+1]*X1.x + kw[oc*4+2]*X2.x + kw[oc*4+3]*X3.x) * g0;
            c.y = (kb[oc] + kw[oc*4+0]*X0.y + kw[oc*4+1]*X1.y + kw[oc*4+2]*X2.y + kw[oc*4+3]*X3.y) * g1;
            c.z = (kb[oc] + kw[oc*4+0]*X0.z + kw[oc*4+1]*X1.z + kw[oc*4+2]*X2.z + kw[oc*4+3]*X3.z) * g2;
            c.w = (kb[oc] + kw[oc*4+0]*X0.w + kw[oc*4+1]*X1.w + kw[oc*4+2]*X2.w + kw[oc*4+3]*X3.w) * g3;
            *(float4*)(ob + (size_t)oc * HW + off) = c;
        }
    }
}

extern "C" void kernel_launch(void* const* d_in, const int* in_sizes, int n_in,
                              void* d_out, int out_size, void* d_ws, size_t ws_size,
                              hipStream_t stream) {
    const float* x      = (const float*)d_in[0];
    const float* ca_w1  = (const float*)d_in[1];
    const float* ca_b1  = (const float*)d_in[2];
    const float* ca_w2  = (const float*)d_in[3];
    const float* ca_b2  = (const float*)d_in[4];
    const float* conv_w = (const float*)d_in[5];
    const float* conv_b = (const float*)d_in[6];
    const float* sa_w   = (const float*)d_in[7];
    const float* sa_b   = (const float*)d_in[8];
    float* ws  = (float*)d_ws;
    float* out = (float*)d_out;

    hipLaunchKernelGGL(k_reduce, dim3(1024), dim3(256), 0, stream, x, ws);
    hipLaunchKernelGGL(k_mlp, dim3(1), dim3(128), 0, stream,
                       ws, ca_w1, ca_b1, ca_w2, ca_b2, ws + 1024);
    hipLaunchKernelGGL(k_fused, dim3(512 / TSX, 512 / TSY, 32), dim3(256), 0, stream,
                       x, conv_w, conv_b, sa_w, sa_b, ws + 1024, out);
}

// Round 7
// 105.577 us; speedup vs baseline: 1.8242x; 1.8242x over previous
//
#include <hip/hip_runtime.h>
#include <math.h>

#define HW (512*512)
#define STRIPW 128
#define STRIPH 64
#define RING 24              // LDS ring rows (window 22 needed; stage overwrites post-barrier)
#define LSTR 136             // dwords per ring row = 34 quads (128 + 8 halo), 8-bank row stagger
#define CHS (RING*LSTR)      // per-channel dwords

// ---------------- Kernel 1: per-plane partial sums (global avg pool) ----------------
__global__ __launch_bounds__(256) void k_reduce(const float* __restrict__ x,
                                                float* __restrict__ ws) {
    int bid = blockIdx.x;            // 1024 blocks = 128 planes * 8 chunks
    int plane = bid >> 3, j = bid & 7;
    const float4* xv = (const float4*)x + (size_t)plane * 65536 + (size_t)j * 8192;
    int tid = threadIdx.x;
    float s = 0.f;
    #pragma unroll
    for (int k = 0; k < 32; ++k) {
        float4 v = xv[(size_t)k * 256 + tid];
        s += (v.x + v.y) + (v.z + v.w);
    }
    #pragma unroll
    for (int off = 32; off > 0; off >>= 1) s += __shfl_down(s, off, 64);
    __shared__ float red[4];
    if ((tid & 63) == 0) red[tid >> 6] = s;
    __syncthreads();
    if (tid == 0) ws[bid] = (red[0] + red[1]) + (red[2] + red[3]);
}

// ---------------- Kernel 2: finish pool + channel-attention MLP ----------------
__global__ __launch_bounds__(128) void k_mlp(const float* __restrict__ part,
                                             const float* __restrict__ w1,
                                             const float* __restrict__ b1,
                                             const float* __restrict__ w2,
                                             const float* __restrict__ b2,
                                             float* __restrict__ att_out) {
    __shared__ float pool[128];   // [b][c], b=32, c=4
    __shared__ float hbuf[64];    // [b][r], r=2
    int tid = threadIdx.x;
    float s = 0.f;
    #pragma unroll
    for (int j = 0; j < 8; ++j) s += part[tid * 8 + j];
    pool[tid] = s * (1.f / 262144.f);
    __syncthreads();
    if (tid < 64) {
        int b = tid >> 1, r = tid & 1;
        float h = b1[r];
        #pragma unroll
        for (int c = 0; c < 4; ++c) h += w1[r * 4 + c] * pool[b * 4 + c];
        hbuf[tid] = fmaxf(h, 0.f);          // hbuf[b*2+r]
    }
    __syncthreads();
    {
        int b = tid >> 2, c = tid & 3;
        float z = b2[c];
        #pragma unroll
        for (int r = 0; r < 2; ++r) z += w2[c * 2 + r] * hbuf[b * 2 + r];
        att_out[tid] = 1.f / (1.f + __expf(-z));   // att[b*4+c]
    }
}

// ---------------- Kernel 3: fused, pipelined row-rolling strip ----------------
// Block = 128x64 strip, 4 steps of 16 output rows. 24-row LDS ring of gated-1x1
// "pre" (3ch). Per step: issue next-16-rows' global loads to regs (T14), conv
// current 16 rows (hides latency), barrier, gate+ds_write held regs into ring,
// barrier. Ring slot = rr % 24 where rr = gy - (sy0-3); conv step s window
// rr = 16s..16s+21, stage rr = 16s+22..16s+37 (overwrites rows conv just used).
__global__ __launch_bounds__(256, 4) void k_fused(const float* __restrict__ x,
                                                  const float* __restrict__ conv_w,
                                                  const float* __restrict__ conv_b,
                                                  const float* __restrict__ sa_w,
                                                  const float* __restrict__ sa_b,
                                                  const float* __restrict__ att,
                                                  float* __restrict__ out) {
    __shared__ float s_pre[3 * CHS];   // 39,168 B -> 4 blocks/CU
    int tid = threadIdx.x;
    int b = blockIdx.z;
    int x0 = blockIdx.x * STRIPW, sy0 = blockIdx.y * STRIPH;
    int tx4 = tid & 31, ty2 = tid >> 5;   // 32 col-threads (4 px), 8 row-threads (2 rows)

    // uniform params (scalar loads)
    float kw[12], kb[3];
    #pragma unroll
    for (int t = 0; t < 12; ++t) kw[t] = conv_w[t] * att[b * 4 + (t & 3)];
    #pragma unroll
    for (int o = 0; o < 3; ++o) kb[o] = conv_b[o];
    float sbias = sa_b[0];
    const float* xb = x + (size_t)b * 4 * HW;
    float* ob = out + (size_t)b * 3 * HW;

#define GATE_STORE(X0_, X1_, X2_, X3_, inb_, slot_, q_)                              \
    {                                                                                \
        float4 o0 = make_float4(0.f,0.f,0.f,0.f), o1 = o0, o2 = o0;                  \
        if (inb_) {                                                                  \
            float kb0 = kb[0], kb1 = kb[1], kb2 = kb[2];                             \
            o0.x = kb0 + kw[0]*X0_.x + kw[1]*X1_.x + kw[2]*X2_.x + kw[3]*X3_.x;      \
            o0.y = kb0 + kw[0]*X0_.y + kw[1]*X1_.y + kw[2]*X2_.y + kw[3]*X3_.y;      \
            o0.z = kb0 + kw[0]*X0_.z + kw[1]*X1_.z + kw[2]*X2_.z + kw[3]*X3_.z;      \
            o0.w = kb0 + kw[0]*X0_.w + kw[1]*X1_.w + kw[2]*X2_.w + kw[3]*X3_.w;      \
            o1.x = kb1 + kw[4]*X0_.x + kw[5]*X1_.x + kw[6]*X2_.x + kw[7]*X3_.x;      \
            o1.y = kb1 + kw[4]*X0_.y + kw[5]*X1_.y + kw[6]*X2_.y + kw[7]*X3_.y;      \
            o1.z = kb1 + kw[4]*X0_.z + kw[5]*X1_.z + kw[6]*X2_.z + kw[7]*X3_.z;      \
            o1.w = kb1 + kw[4]*X0_.w + kw[5]*X1_.w + kw[6]*X2_.w + kw[7]*X3_.w;      \
            o2.x = kb2 + kw[8]*X0_.x + kw[9]*X1_.x + kw[10]*X2_.x + kw[11]*X3_.x;    \
            o2.y = kb2 + kw[8]*X0_.y + kw[9]*X1_.y + kw[10]*X2_.y + kw[11]*X3_.y;    \
            o2.z = kb2 + kw[8]*X0_.z + kw[9]*X1_.z + kw[10]*X2_.z + kw[11]*X3_.z;    \
            o2.w = kb2 + kw[8]*X0_.w + kw[9]*X1_.w + kw[10]*X2_.w + kw[11]*X3_.w;    \
        }                                                                            \
        int base_ = (slot_) * LSTR + ((q_) << 2);                                    \
        *(float4*)(&s_pre[base_])           = o0;                                    \
        *(float4*)(&s_pre[base_ + CHS])     = o1;                                    \
        *(float4*)(&s_pre[base_ + 2*CHS])   = o2;                                    \
    }

    // ---- Prologue: stage rows rr=0..21 (gy = sy0-3 .. sy0+18), slot = rr ----
    for (int u = tid; u < 22 * 34; u += 256) {
        int rr = u / 34, q = u - rr * 34;
        int gy = sy0 - 3 + rr;
        int gx0 = x0 - 4 + q * 4;
        bool inb = ((unsigned)gy < 512u) && ((unsigned)gx0 <= 508u);
        float4 X0 = make_float4(0.f,0.f,0.f,0.f), X1 = X0, X2 = X0, X3 = X0;
        if (inb) {
            size_t off = (size_t)gy * 512 + gx0;
            X0 = *(const float4*)(xb + off);
            X1 = *(const float4*)(xb + HW + off);
            X2 = *(const float4*)(xb + 2 * HW + off);
            X3 = *(const float4*)(xb + 3 * HW + off);
        }
        GATE_STORE(X0, X1, X2, X3, inb, rr, q)
    }
    __syncthreads();

    // ---- Steps ----
    for (int s = 0; s < 4; ++s) {
        int sbase  = (0x00081000 >> (8 * s)) & 31;   // (16s)%24: {0,16,8,0}
        int sb22   = (0x00060E16 >> (8 * s)) & 31;   // (16s+22)%24: {22,14,6,(unused)}

        // (a) issue next-step staging loads into registers (T14 issue-early)
        float4 Ld[3][4];
        bool   linb[3];
        int    lr_[3], lq_[3];
        #pragma unroll
        for (int t = 0; t < 3; ++t) {
            linb[t] = false; lr_[t] = 0; lq_[t] = 0;
            Ld[t][0] = make_float4(0.f,0.f,0.f,0.f);
            Ld[t][1] = Ld[t][0]; Ld[t][2] = Ld[t][0]; Ld[t][3] = Ld[t][0];
        }
        if (s < 3) {
            #pragma unroll
            for (int t = 0; t < 3; ++t) {
                int u = tid + t * 256;
                if (u < 16 * 34) {
                    int r = u / 34, q = u - r * 34;
                    int gy = sy0 + 16 * s + 19 + r;
                    int gx0 = x0 - 4 + q * 4;
                    bool inb = ((unsigned)gy < 512u) && ((unsigned)gx0 <= 508u);
                    lr_[t] = r; lq_[t] = q; linb[t] = inb;
                    if (inb) {
                        size_t off = (size_t)gy * 512 + gx0;
                        Ld[t][0] = *(const float4*)(xb + off);
                        Ld[t][1] = *(const float4*)(xb + HW + off);
                        Ld[t][2] = *(const float4*)(xb + 2 * HW + off);
                        Ld[t][3] = *(const float4*)(xb + 3 * HW + off);
                    }
                }
            }
        }

        // (b) conv current 16 rows: thread owns 4 cols x 2 rows
        float acc[2][4] = {{0.f,0.f,0.f,0.f},{0.f,0.f,0.f,0.f}};
        #pragma unroll
        for (int ch = 0; ch < 3; ++ch) {
            const float* sbp = &s_pre[ch * CHS];
            const float* wp = sa_w + ch * 49;
            #pragma unroll
            for (int k = 0; k < 8; ++k) {
                int sl = sbase + ty2 * 2 + k;
                if (sl >= RING) sl -= RING;
                int rb = sl * LSTR + (tx4 << 2);
                float4 va = *(const float4*)(sbp + rb);
                float4 vb = *(const float4*)(sbp + rb + 4);
                float4 vc = *(const float4*)(sbp + rb + 8);
                float v[12] = {va.x, va.y, va.z, va.w,
                               vb.x, vb.y, vb.z, vb.w,
                               vc.x, vc.y, vc.z, vc.w};
                #pragma unroll
                for (int i = 0; i < 2; ++i) {
                    int dy = k - i;
                    if (dy >= 0 && dy < 7) {
                        #pragma unroll
                        for (int dx = 0; dx < 7; ++dx) {
                            float wv = wp[dy * 7 + dx];   // uniform -> s_load
                            #pragma unroll
                            for (int j = 0; j < 4; ++j)
                                acc[i][j] += wv * v[j + dx + 1];
                        }
                    }
                }
            }
        }

        // epilogue for this step: reload centers from LDS (slots still valid), gate, store
        #pragma unroll
        for (int i = 0; i < 2; ++i) {
            int sl = sbase + ty2 * 2 + i + 3;
            if (sl >= RING) sl -= RING;
            int rb = sl * LSTR + (tx4 << 2) + 4;     // center quad
            float4 c0 = *(const float4*)(&s_pre[rb]);
            float4 c1 = *(const float4*)(&s_pre[rb + CHS]);
            float4 c2 = *(const float4*)(&s_pre[rb + 2 * CHS]);
            float g0 = 1.f / (1.f + __expf(-(acc[i][0] + sbias)));
            float g1 = 1.f / (1.f + __expf(-(acc[i][1] + sbias)));
            float g2 = 1.f / (1.f + __expf(-(acc[i][2] + sbias)));
            float g3 = 1.f / (1.f + __expf(-(acc[i][3] + sbias)));
            c0.x *= g0; c0.y *= g1; c0.z *= g2; c0.w *= g3;
            c1.x *= g0; c1.y *= g1; c1.z *= g2; c1.w *= g3;
            c2.x *= g0; c2.y *= g1; c2.z *= g2; c2.w *= g3;
            int oy = sy0 + 16 * s + ty2 * 2 + i;
            size_t off = (size_t)oy * 512 + (x0 + tx4 * 4);
            *(float4*)(ob + off)          = c0;
            *(float4*)(ob + HW + off)     = c1;
            *(float4*)(ob + 2 * HW + off) = c2;
        }

        // (c) all conv reads of old rows done
        __syncthreads();

        // (d) gate + write held registers into ring (rows rr = 16s+22..16s+37)
        if (s < 3) {
            #pragma unroll
            for (int t = 0; t < 3; ++t) {
                int u = tid + t * 256;
                if (u < 16 * 34) {
                    int slot2 = sb22 + lr_[t];
                    if (slot2 >= RING) slot2 -= RING;
                    GATE_STORE(Ld[t][0], Ld[t][1], Ld[t][2], Ld[t][3], linb[t], slot2, lq_[t])
                }
            }
        }
        // (e) ring updated for next step
        __syncthreads();
    }
#undef GATE_STORE
}

extern "C" void kernel_launch(void* const* d_in, const int* in_sizes, int n_in,
                              void* d_out, int out_size, void* d_ws, size_t ws_size,
                              hipStream_t stream) {
    const float* x      = (const float*)d_in[0];
    const float* ca_w1  = (const float*)d_in[1];
    const float* ca_b1  = (const float*)d_in[2];
    const float* ca_w2  = (const float*)d_in[3];
    const float* ca_b2  = (const float*)d_in[4];
    const float* conv_w = (const float*)d_in[5];
    const float* conv_b = (const float*)d_in[6];
    const float* sa_w   = (const float*)d_in[7];
    const float* sa_b   = (const float*)d_in[8];
    float* ws  = (float*)d_ws;
    float* out = (float*)d_out;

    hipLaunchKernelGGL(k_reduce, dim3(1024), dim3(256), 0, stream, x, ws);
    hipLaunchKernelGGL(k_mlp, dim3(1), dim3(128), 0, stream,
                       ws, ca_w1, ca_b1, ca_w2, ca_b2, ws + 1024);
    hipLaunchKernelGGL(k_fused, dim3(512 / STRIPW, 512 / STRIPH, 32), dim3(256), 0, stream,
                       x, conv_w, conv_b, sa_w, sa_b, ws + 1024, out);
}

// Round 8
// 93.200 us; speedup vs baseline: 2.0664x; 1.1328x over previous
//
#include <hip/hip_runtime.h>
#include <math.h>

#define HW (512*512)
#define TSX 64
#define TSY 32
#define NROW 38              // TSY + 6 halo rows
#define LSTR 80              // dwords per LDS row (20 quads; logical quads 0..17, swizzled <=19)
#define CH_STRIDE (NROW*LSTR)

// ---------------- Kernel 1: per-plane partial sums (global avg pool) ----------------
__global__ __launch_bounds__(256) void k_reduce(const float* __restrict__ x,
                                                float* __restrict__ ws) {
    int bid = blockIdx.x;            // 1024 blocks = 128 planes * 8 chunks
    int plane = bid >> 3, j = bid & 7;
    const float4* xv = (const float4*)x + (size_t)plane * 65536 + (size_t)j * 8192;
    int tid = threadIdx.x;
    float s = 0.f;
    #pragma unroll
    for (int k = 0; k < 32; ++k) {
        float4 v = xv[(size_t)k * 256 + tid];
        s += (v.x + v.y) + (v.z + v.w);
    }
    #pragma unroll
    for (int off = 32; off > 0; off >>= 1) s += __shfl_down(s, off, 64);
    __shared__ float red[4];
    if ((tid & 63) == 0) red[tid >> 6] = s;
    __syncthreads();
    if (tid == 0) ws[bid] = (red[0] + red[1]) + (red[2] + red[3]);
}

// ---------------- Kernel 2: finish pool + channel-attention MLP ----------------
__global__ __launch_bounds__(128) void k_mlp(const float* __restrict__ part,
                                             const float* __restrict__ w1,
                                             const float* __restrict__ b1,
                                             const float* __restrict__ w2,
                                             const float* __restrict__ b2,
                                             float* __restrict__ att_out) {
    __shared__ float pool[128];   // [b][c], b=32, c=4
    __shared__ float hbuf[64];    // [b][r], r=2
    int tid = threadIdx.x;
    float s = 0.f;
    #pragma unroll
    for (int j = 0; j < 8; ++j) s += part[tid * 8 + j];
    pool[tid] = s * (1.f / 262144.f);
    __syncthreads();
    if (tid < 64) {
        int b = tid >> 1, r = tid & 1;
        float h = b1[r];
        #pragma unroll
        for (int c = 0; c < 4; ++c) h += w1[r * 4 + c] * pool[b * 4 + c];
        hbuf[tid] = fmaxf(h, 0.f);          // hbuf[b*2+r]
    }
    __syncthreads();
    {
        int b = tid >> 2, c = tid & 3;
        float z = b2[c];
        #pragma unroll
        for (int r = 0; r < 2; ++r) z += w2[c * 2 + r] * hbuf[b * 2 + r];
        att_out[tid] = 1.f / (1.f + __expf(-z));   // att[b*4+c]
    }
}

// ---------------- Kernel 3: fused gate + 1x1 conv + 7x7 conv + sigmoid gate ----------------
// R3 structure (87 us): tile 64x32, 4x2 px/thread, LSTR=80, XOR swizzle key
// (row>>1)&3 on quad index (write+read). ONE change: ch loop is runtime
// non-unrolled; each iteration preloads its 49 weights into SGPR-resident w[]
// so no s_load (SMEM, lgkmcnt-shared) lands inside the ds_read+FMA stream.
__global__ __launch_bounds__(256, 4) void k_fused(const float* __restrict__ x,
                                                  const float* __restrict__ conv_w,
                                                  const float* __restrict__ conv_b,
                                                  const float* __restrict__ sa_w,
                                                  const float* __restrict__ sa_b,
                                                  const float* __restrict__ att,
                                                  float* __restrict__ out) {
    __shared__ float s_out[3 * CH_STRIDE];   // 36,480 B -> 4 blocks/CU
    int tid = threadIdx.x;
    int b = blockIdx.z;
    int ty0 = blockIdx.y * TSY, tx0 = blockIdx.x * TSX;

    // uniform params
    float kw[12], kb[3];
    #pragma unroll
    for (int t = 0; t < 12; ++t) kw[t] = conv_w[t] * att[b * 4 + (t & 3)];
    #pragma unroll
    for (int o = 0; o < 3; ++o) kb[o] = conv_b[o];
    float sbias = sa_b[0];

    // ---- Stage: gated 1x1 conv for tile+halo into LDS (swizzled b128 writes) ----
    const float* xb = x + (size_t)b * 4 * HW;
    for (int idx = tid; idx < NROW * 18; idx += 256) {
        int r = idx / 18, q = idx - r * 18;
        int gy = ty0 - 3 + r;
        int gx0 = tx0 - 4 + q * 4;
        float4 o0 = make_float4(0.f, 0.f, 0.f, 0.f), o1 = o0, o2 = o0;
        if ((unsigned)gy < 512u && (unsigned)gx0 <= 508u) {
            size_t off = (size_t)gy * 512 + gx0;
            float4 X0 = *(const float4*)(xb + off);
            float4 X1 = *(const float4*)(xb + HW + off);
            float4 X2 = *(const float4*)(xb + 2 * HW + off);
            float4 X3 = *(const float4*)(xb + 3 * HW + off);
#define DO1(comp) \
            o0.comp = kb[0] + kw[0]*X0.comp + kw[1]*X1.comp + kw[2]*X2.comp + kw[3]*X3.comp; \
            o1.comp = kb[1] + kw[4]*X0.comp + kw[5]*X1.comp + kw[6]*X2.comp + kw[7]*X3.comp; \
            o2.comp = kb[2] + kw[8]*X0.comp + kw[9]*X1.comp + kw[10]*X2.comp + kw[11]*X3.comp;
            DO1(x) DO1(y) DO1(z) DO1(w)
#undef DO1
        }
        int base = r * LSTR + (((q ^ ((r >> 1) & 3)) << 2));
        *(float4*)(&s_out[base])                 = o0;
        *(float4*)(&s_out[base + CH_STRIDE])     = o1;
        *(float4*)(&s_out[base + 2 * CH_STRIDE]) = o2;
    }
    __syncthreads();

    // ---- 7x7 conv: thread computes 4 cols x 2 rows ----
    int tx4 = tid & 15, ty2 = tid >> 4;   // ty2 0..15 -> out rows 2*ty2, 2*ty2+1
    float acc[2][4] = {{0.f, 0.f, 0.f, 0.f}, {0.f, 0.f, 0.f, 0.f}};

    #pragma clang loop unroll(disable)
    for (int ch = 0; ch < 3; ++ch) {
        const float* sbp = &s_out[ch * CH_STRIDE];
        // preload this channel's 49 weights (uniform s_loads, OUTSIDE the hot loop)
        float w[49];
        #pragma unroll
        for (int t = 0; t < 49; ++t) w[t] = sa_w[ch * 49 + t];
        #pragma unroll
        for (int k = 0; k < 8; ++k) {
            int lr = ty2 * 2 + k;            // logical row, 0..37
            int key = (lr >> 1) & 3;
            int rb = lr * LSTR;
            float4 va = *(const float4*)(sbp + rb + (((tx4    ) ^ key) << 2));
            float4 vb = *(const float4*)(sbp + rb + (((tx4 + 1) ^ key) << 2));
            float4 vc = *(const float4*)(sbp + rb + (((tx4 + 2) ^ key) << 2));
            float v[12] = {va.x, va.y, va.z, va.w,
                           vb.x, vb.y, vb.z, vb.w,
                           vc.x, vc.y, vc.z, vc.w};
            #pragma unroll
            for (int i = 0; i < 2; ++i) {
                int dy = k - i;
                if (dy >= 0 && dy <= 6) {
                    #pragma unroll
                    for (int dx = 0; dx < 7; ++dx) {
                        float wv = w[dy * 7 + dx];
                        #pragma unroll
                        for (int j = 0; j < 4; ++j)
                            acc[i][j] += wv * v[j + dx + 1];
                    }
                }
            }
        }
    }

    // ---- Epilogue: sigmoid gate + b128 stores ----
    float* ob = out + (size_t)b * 3 * HW;
    #pragma unroll
    for (int i = 0; i < 2; ++i) {
        int oy = ty2 * 2 + i;                // 0..31
        int lr = oy + 3;                     // center row
        int key = (lr >> 1) & 3;
        int base = lr * LSTR + (((tx4 + 1) ^ key) << 2);
        float4 c0 = *(const float4*)(&s_out[base]);
        float4 c1 = *(const float4*)(&s_out[base + CH_STRIDE]);
        float4 c2 = *(const float4*)(&s_out[base + 2 * CH_STRIDE]);
        float g0 = 1.f / (1.f + __expf(-(acc[i][0] + sbias)));
        float g1 = 1.f / (1.f + __expf(-(acc[i][1] + sbias)));
        float g2 = 1.f / (1.f + __expf(-(acc[i][2] + sbias)));
        float g3 = 1.f / (1.f + __expf(-(acc[i][3] + sbias)));
        c0.x *= g0; c0.y *= g1; c0.z *= g2; c0.w *= g3;
        c1.x *= g0; c1.y *= g1; c1.z *= g2; c1.w *= g3;
        c2.x *= g0; c2.y *= g1; c2.z *= g2; c2.w *= g3;
        size_t off = (size_t)(ty0 + oy) * 512 + (tx0 + tx4 * 4);
        *(float4*)(ob + off)          = c0;
        *(float4*)(ob + HW + off)     = c1;
        *(float4*)(ob + 2 * HW + off) = c2;
    }
}

extern "C" void kernel_launch(void* const* d_in, const int* in_sizes, int n_in,
                              void* d_out, int out_size, void* d_ws, size_t ws_size,
                              hipStream_t stream) {
    const float* x      = (const float*)d_in[0];
    const float* ca_w1  = (const float*)d_in[1];
    const float* ca_b1  = (const float*)d_in[2];
    const float* ca_w2  = (const float*)d_in[3];
    const float* ca_b2  = (const float*)d_in[4];
    const float* conv_w = (const float*)d_in[5];
    const float* conv_b = (const float*)d_in[6];
    const float* sa_w   = (const float*)d_in[7];
    const float* sa_b   = (const float*)d_in[8];
    float* ws  = (float*)d_ws;
    float* out = (float*)d_out;

    hipLaunchKernelGGL(k_reduce, dim3(1024), dim3(256), 0, stream, x, ws);
    hipLaunchKernelGGL(k_mlp, dim3(1), dim3(128), 0, stream,
                       ws, ca_w1, ca_b1, ca_w2, ca_b2, ws + 1024);
    hipLaunchKernelGGL(k_fused, dim3(8, 16, 32), dim3(256), 0, stream,
                       x, conv_w, conv_b, sa_w, sa_b, ws + 1024, out);
}

// Round 10
// 89.589 us; speedup vs baseline: 2.1497x; 1.0403x over previous
//
#include <hip/hip_runtime.h>
#include <math.h>
#include <stdint.h>

#define HW (512*512)
#define TSX 128
#define TSY 32
#define NROW 38              // TSY + 6 halo rows
#define LSTRH 76             // dwords per LDS row (72 used = 144 fp16 px, +4 pad; 76%32=12 row stagger)
#define CHS (NROW*LSTRH)

typedef __fp16 h2 __attribute__((ext_vector_type(2)));   // matches cvt_pkrtz / fdot2 types

__device__ __forceinline__ h2 u2h(uint32_t u) { union { uint32_t u; h2 h; } c; c.u = u; return c.h; }
__device__ __forceinline__ uint32_t h2u(h2 h) { union { h2 h; uint32_t u; } c; c.h = h; return c.u; }

#if __has_builtin(__builtin_amdgcn_fdot2)
#define FDOT2(a, b, c) __builtin_amdgcn_fdot2((a), (b), (c), false)
#else
__device__ __forceinline__ float fdot2_asm(h2 a, h2 b, float c) {
    float d;
    asm("v_dot2_f32_f16 %0, %1, %2, %3" : "=v"(d) : "v"(a), "v"(b), "v"(c));
    return d;
}
#define FDOT2(a, b, c) fdot2_asm((a), (b), (c))
#endif

// ---------------- Kernel 1: per-plane partial sums (global avg pool) ----------------
__global__ __launch_bounds__(256) void k_reduce(const float* __restrict__ x,
                                                float* __restrict__ ws) {
    int bid = blockIdx.x;            // 1024 blocks = 128 planes * 8 chunks
    int plane = bid >> 3, j = bid & 7;
    const float4* xv = (const float4*)x + (size_t)plane * 65536 + (size_t)j * 8192;
    int tid = threadIdx.x;
    float s = 0.f;
    #pragma unroll
    for (int k = 0; k < 32; ++k) {
        float4 v = xv[(size_t)k * 256 + tid];
        s += (v.x + v.y) + (v.z + v.w);
    }
    #pragma unroll
    for (int off = 32; off > 0; off >>= 1) s += __shfl_down(s, off, 64);
    __shared__ float red[4];
    if ((tid & 63) == 0) red[tid >> 6] = s;
    __syncthreads();
    if (tid == 0) ws[bid] = (red[0] + red[1]) + (red[2] + red[3]);
}

// ---------------- Kernel 2: finish pool + channel-attention MLP ----------------
__global__ __launch_bounds__(128) void k_mlp(const float* __restrict__ part,
                                             const float* __restrict__ w1,
                                             const float* __restrict__ b1,
                                             const float* __restrict__ w2,
                                             const float* __restrict__ b2,
                                             float* __restrict__ att_out) {
    __shared__ float pool[128];   // [b][c], b=32, c=4
    __shared__ float hbuf[64];    // [b][r], r=2
    int tid = threadIdx.x;
    float s = 0.f;
    #pragma unroll
    for (int j = 0; j < 8; ++j) s += part[tid * 8 + j];
    pool[tid] = s * (1.f / 262144.f);
    __syncthreads();
    if (tid < 64) {
        int b = tid >> 1, r = tid & 1;
        float h = b1[r];
        #pragma unroll
        for (int c = 0; c < 4; ++c) h += w1[r * 4 + c] * pool[b * 4 + c];
        hbuf[tid] = fmaxf(h, 0.f);          // hbuf[b*2+r]
    }
    __syncthreads();
    {
        int b = tid >> 2, c = tid & 3;
        float z = b2[c];
        #pragma unroll
        for (int r = 0; r < 2; ++r) z += w2[c * 2 + r] * hbuf[b * 2 + r];
        att_out[tid] = 1.f / (1.f + __expf(-z));   // att[b*4+c]
    }
}

// ---------------- Kernel 3: fused gate + 1x1 conv + 7x7 conv + sigmoid gate ----------------
// Tile 128x32, 256 threads, thread owns 8 cols x 2 rows (txi=tid&15, tyr=tid>>4).
// Staged gated-1x1 "pre" stored as packed fp16 in LDS (34.7 KB -> 4 blocks/CU).
// Conv via v_dot2_f32_f16 (2 MAC/instr, f32 accumulate). Per (k-row, ch):
// 3 aligned b128 reads (24 px), 7 v_alignbit for odd-offset half2 pairs,
// weights SGPR-resident (R8 lesson), packed per-dy with cvt_pkrtz.
// LDS px origin: px P = gx - (tx0 - 8); thread reads P = 8*txi .. 8*txi+23.
__global__ __launch_bounds__(256, 4) void k_fused(const float* __restrict__ x,
                                                  const float* __restrict__ conv_w,
                                                  const float* __restrict__ conv_b,
                                                  const float* __restrict__ sa_w,
                                                  const float* __restrict__ sa_b,
                                                  const float* __restrict__ att,
                                                  float* __restrict__ out) {
    __shared__ uint32_t s_pre[3 * CHS];   // 34,656 B
    int tid = threadIdx.x;
    int b = blockIdx.z;
    int ty0 = blockIdx.y * TSY, tx0 = blockIdx.x * TSX;

    // uniform params
    float kw[12], kb[3];
    #pragma unroll
    for (int t = 0; t < 12; ++t) kw[t] = conv_w[t] * att[b * 4 + (t & 3)];
    #pragma unroll
    for (int o = 0; o < 3; ++o) kb[o] = conv_b[o];
    float sbias = sa_b[0];
    const float* xb = x + (size_t)b * 4 * HW;

    // ---- Stage: gated 1x1 conv for tile+halo, packed fp16 into LDS ----
    // row r (0..37): gy = ty0-3+r; quad q (0..35): gx0 = tx0-8+4q (aligned, all-in or all-out)
    for (int u = tid; u < NROW * 36; u += 256) {
        int r = u / 36, q = u - r * 36;
        int gy = ty0 - 3 + r;
        int gx0 = tx0 - 8 + q * 4;
        float4 o0 = make_float4(0.f, 0.f, 0.f, 0.f), o1 = o0, o2 = o0;
        if ((unsigned)gy < 512u && (unsigned)gx0 <= 508u) {
            size_t off = (size_t)gy * 512 + gx0;
            float4 X0 = *(const float4*)(xb + off);
            float4 X1 = *(const float4*)(xb + HW + off);
            float4 X2 = *(const float4*)(xb + 2 * HW + off);
            float4 X3 = *(const float4*)(xb + 3 * HW + off);
#define DO1(comp) \
            o0.comp = kb[0] + kw[0]*X0.comp + kw[1]*X1.comp + kw[2]*X2.comp + kw[3]*X3.comp; \
            o1.comp = kb[1] + kw[4]*X0.comp + kw[5]*X1.comp + kw[6]*X2.comp + kw[7]*X3.comp; \
            o2.comp = kb[2] + kw[8]*X0.comp + kw[9]*X1.comp + kw[10]*X2.comp + kw[11]*X3.comp;
            DO1(x) DO1(y) DO1(z) DO1(w)
#undef DO1
        }
        int base = r * LSTRH + 2 * q;
        uint2 w0 = make_uint2(h2u(__builtin_amdgcn_cvt_pkrtz(o0.x, o0.y)),
                              h2u(__builtin_amdgcn_cvt_pkrtz(o0.z, o0.w)));
        uint2 w1 = make_uint2(h2u(__builtin_amdgcn_cvt_pkrtz(o1.x, o1.y)),
                              h2u(__builtin_amdgcn_cvt_pkrtz(o1.z, o1.w)));
        uint2 w2 = make_uint2(h2u(__builtin_amdgcn_cvt_pkrtz(o2.x, o2.y)),
                              h2u(__builtin_amdgcn_cvt_pkrtz(o2.z, o2.w)));
        *(uint2*)(&s_pre[base])           = w0;
        *(uint2*)(&s_pre[base + CHS])     = w1;
        *(uint2*)(&s_pre[base + 2 * CHS]) = w2;
    }
    __syncthreads();

    // ---- 7x7 conv: thread computes 8 cols x 2 rows via dot2 ----
    int txi = tid & 15, tyr = tid >> 4;   // out rows 2*tyr, 2*tyr+1; cols tx0+8*txi..+7
    float acc[2][8];
    #pragma unroll
    for (int i = 0; i < 2; ++i)
        #pragma unroll
        for (int j = 0; j < 8; ++j) acc[i][j] = 0.f;

    #pragma clang loop unroll(disable)
    for (int ch = 0; ch < 3; ++ch) {
        const uint32_t* sbp = &s_pre[ch * CHS];
        // preload this channel's 49 weights (uniform -> SGPRs, outside hot loop)
        float wch[49];
        #pragma unroll
        for (int t = 0; t < 49; ++t) wch[t] = sa_w[ch * 49 + t];
        #pragma unroll
        for (int k = 0; k < 8; ++k) {
            int lr = 2 * tyr + k;                      // logical row 0..37
            const uint32_t* rowp = sbp + lr * LSTRH + 4 * txi;
            uint4 ra = *(const uint4*)(rowp);
            uint4 rb = *(const uint4*)(rowp + 4);
            uint4 rc = *(const uint4*)(rowp + 8);
            uint32_t r_[12] = {ra.x, ra.y, ra.z, ra.w,
                               rb.x, rb.y, rb.z, rb.w,
                               rc.x, rc.y, rc.z, rc.w};
            // half2 pairs pr[h] = (px h, px h+1), h relative to px 8*txi; need h=5..18
            uint32_t pr[19];
            #pragma unroll
            for (int m = 3; m <= 9; ++m) pr[2 * m] = r_[m];
            #pragma unroll
            for (int m = 2; m <= 8; ++m)
                pr[2 * m + 1] = __builtin_amdgcn_alignbit(r_[m + 1], r_[m], 16);
            #pragma unroll
            for (int i = 0; i < 2; ++i) {
                int dy = k - i;
                if (dy >= 0 && dy <= 6) {
                    h2 w01 = __builtin_amdgcn_cvt_pkrtz(wch[dy * 7 + 0], wch[dy * 7 + 1]);
                    h2 w23 = __builtin_amdgcn_cvt_pkrtz(wch[dy * 7 + 2], wch[dy * 7 + 3]);
                    h2 w45 = __builtin_amdgcn_cvt_pkrtz(wch[dy * 7 + 4], wch[dy * 7 + 5]);
                    h2 w6z = __builtin_amdgcn_cvt_pkrtz(wch[dy * 7 + 6], 0.f);
                    #pragma unroll
                    for (int j = 0; j < 8; ++j) {
                        float a = acc[i][j];
                        a = FDOT2(w01, u2h(pr[j + 5]), a);
                        a = FDOT2(w23, u2h(pr[j + 7]), a);
                        a = FDOT2(w45, u2h(pr[j + 9]), a);
                        a = FDOT2(w6z, u2h(pr[j + 11]), a);
                        acc[i][j] = a;
                    }
                }
            }
        }
    }

    // ---- Epilogue: sigmoid gate, centers from LDS (b128), f32 stores ----
    float* ob = out + (size_t)b * 3 * HW;
    #pragma unroll
    for (int i = 0; i < 2; ++i) {
        float g[8];
        #pragma unroll
        for (int j = 0; j < 8; ++j) g[j] = 1.f / (1.f + __expf(-(acc[i][j] + sbias)));
        int lr = 2 * tyr + 3 + i;                      // center row
        size_t off = (size_t)(ty0 + 2 * tyr + i) * 512 + (tx0 + 8 * txi);
        #pragma unroll
        for (int ch = 0; ch < 3; ++ch) {
            const uint32_t* cp = &s_pre[ch * CHS + lr * LSTRH + 4 * txi + 4];
            uint4 cv = *(const uint4*)cp;              // px 8*txi+8 .. +15 (centers)
            h2 c0 = u2h(cv.x), c1 = u2h(cv.y), c2 = u2h(cv.z), c3 = u2h(cv.w);
            float4 A, B;
            A.x = (float)c0.x * g[0]; A.y = (float)c0.y * g[1];
            A.z = (float)c1.x * g[2]; A.w = (float)c1.y * g[3];
            B.x = (float)c2.x * g[4]; B.y = (float)c2.y * g[5];
            B.z = (float)c3.x * g[6]; B.w = (float)c3.y * g[7];
            *(float4*)(ob + (size_t)ch * HW + off)     = A;
            *(float4*)(ob + (size_t)ch * HW + off + 4) = B;
        }
    }
}

extern "C" void kernel_launch(void* const* d_in, const int* in_sizes, int n_in,
                              void* d_out, int out_size, void* d_ws, size_t ws_size,
                              hipStream_t stream) {
    const float* x      = (const float*)d_in[0];
    const float* ca_w1  = (const float*)d_in[1];
    const float* ca_b1  = (const float*)d_in[2];
    const float* ca_w2  = (const float*)d_in[3];
    const float* ca_b2  = (const float*)d_in[4];
    const float* conv_w = (const float*)d_in[5];
    const float* conv_b = (const float*)d_in[6];
    const float* sa_w   = (const float*)d_in[7];
    const float* sa_b   = (const float*)d_in[8];
    float* ws  = (float*)d_ws;
    float* out = (float*)d_out;

    hipLaunchKernelGGL(k_reduce, dim3(1024), dim3(256), 0, stream, x, ws);
    hipLaunchKernelGGL(k_mlp, dim3(1), dim3(128), 0, stream,
                       ws, ca_w1, ca_b1, ca_w2, ca_b2, ws + 1024);
    hipLaunchKernelGGL(k_fused, dim3(512 / TSX, 512 / TSY, 32), dim3(256), 0, stream,
                       x, conv_w, conv_b, sa_w, sa_b, ws + 1024, out);
}